// Round 6
// baseline (432.163 us; speedup 1.0000x reference)
//
#include <hip/hip_runtime.h>
#include <stdint.h>

typedef __bf16 bf16x8 __attribute__((ext_vector_type(8)));
typedef float f32x4 __attribute__((ext_vector_type(4)));
typedef float f32x2 __attribute__((ext_vector_type(2)));
typedef unsigned short u16x8 __attribute__((ext_vector_type(8)));

__device__ __forceinline__ unsigned short f2bf(float f){
  union { float f; unsigned u; } c; c.f = f;
  unsigned u = c.u;
  unsigned r = u + 0x7FFFu + ((u >> 16) & 1u);
  return (unsigned short)(r >> 16);
}
__device__ __forceinline__ f32x2 bf2x(unsigned p){
  f32x2 r;
  r[0] = __uint_as_float(p << 16);
  r[1] = __uint_as_float(p & 0xffff0000u);
  return r;
}

// ---------------- CSR build (group edges by dst) ----------------
__global__ void k_hist(const int* __restrict__ ei, int E, int Nn, int* __restrict__ counts){
  int total = E + Nn;
  for (int e = blockIdx.x*blockDim.x + threadIdx.x; e < total; e += gridDim.x*blockDim.x){
    int d = (e < E) ? ei[E + e] : (e - E);
    atomicAdd(&counts[d], 1);
  }
}

__global__ __launch_bounds__(1024) void k_scan1(const int* __restrict__ counts, int* __restrict__ rowptr,
                                                int* __restrict__ bsum, int n){
  __shared__ int wsum[17];
  int tid = threadIdx.x, lane = tid & 63, wid = tid >> 6;
  int i = blockIdx.x*1024 + tid;
  int v = (i < n) ? counts[i] : 0;
  int iv = v;
  #pragma unroll
  for (int off = 1; off < 64; off <<= 1){
    int t = __shfl_up(iv, off, 64);
    if (lane >= off) iv += t;
  }
  if (lane == 63) wsum[wid] = iv;
  __syncthreads();
  if (tid == 0){
    int run = 0;
    for (int w = 0; w < 16; ++w){ int t = wsum[w]; wsum[w] = run; run += t; }
    wsum[16] = run;
  }
  __syncthreads();
  if (i < n) rowptr[i + 1] = iv + wsum[wid];
  if (tid == 0) bsum[blockIdx.x] = wsum[16];
}

__global__ __launch_bounds__(1024) void k_scan2(int* __restrict__ bsum, int nb){
  __shared__ int wsum[17];
  int tid = threadIdx.x, lane = tid & 63, wid = tid >> 6;
  int v = (tid < nb) ? bsum[tid] : 0;
  int iv = v;
  #pragma unroll
  for (int off = 1; off < 64; off <<= 1){
    int t = __shfl_up(iv, off, 64);
    if (lane >= off) iv += t;
  }
  if (lane == 63) wsum[wid] = iv;
  __syncthreads();
  if (tid == 0){
    int run = 0;
    for (int w = 0; w < 16; ++w){ int t = wsum[w]; wsum[w] = run; run += t; }
  }
  __syncthreads();
  if (tid < nb) bsum[tid] = iv + wsum[wid] - v;   // exclusive
}

// finalize rowptr and seed cursor[i] = rowptr[i] (segment start) in the same pass
__global__ void k_scan3(int* __restrict__ rowptr, const int* __restrict__ bsum,
                        const int* __restrict__ counts, int* __restrict__ cursor, int n){
  int i = blockIdx.x*blockDim.x + threadIdx.x;
  if (i == 0) rowptr[0] = 0;
  if (i < n){
    int v = rowptr[i + 1] + bsum[i >> 10];
    rowptr[i + 1] = v;
    cursor[i] = v - counts[i];
  }
}

__global__ void k_scatter(const int* __restrict__ ei, int E, int Nn,
                          int* __restrict__ cursor, int* __restrict__ srcs){
  int total = E + Nn;
  for (int e = blockIdx.x*blockDim.x + threadIdx.x; e < total; e += gridDim.x*blockDim.x){
    int s, d;
    if (e < E){ s = ei[e]; d = ei[E + e]; } else { s = d = e - E; }
    int pos = atomicAdd(&cursor[d], 1);
    srcs[pos] = s;
  }
}

// all three weight transposes in one launch
__global__ void k_transpose_all(const float* __restrict__ W1, const float* __restrict__ W2,
                                const float* __restrict__ W3, unsigned short* __restrict__ wt1,
                                unsigned short* __restrict__ wt2, unsigned short* __restrict__ wt3){
  int t = blockIdx.x*blockDim.x + threadIdx.x;
  int which = t >> 16, li = t & 65535;
  int k = li >> 8, c = li & 255;
  const float* W = (which == 0) ? W1 : (which == 1) ? W2 : W3;
  unsigned short* Wt = (which == 0) ? wt1 : (which == 1) ? wt2 : wt3;
  Wt[c*256 + k] = f2bf(W[k*256 + c]);
}

// ---------------- pipelined GEMM + LDS-bounced coalesced C store + logit epilogue ----------------
// 512 threads = 8 waves; tile 64 rows x 256 cols; 2 tiles per block (t and t+G).
template<bool AF32>
__global__ __launch_bounds__(512) void k_gemm4(const void* __restrict__ Av,
                                               const unsigned short* __restrict__ Wt,
                                               const float* __restrict__ asrc,
                                               const float* __restrict__ adst,
                                               unsigned short* __restrict__ H,
                                               float* __restrict__ als,
                                               float* __restrict__ ald,
                                               int Nn, int T, int G){
  __shared__ unsigned short As[64][264];
  int tid = threadIdx.x;
  int wid = tid >> 6, lane = tid & 63;
  int w = wid & 3, rh = wid >> 2;
  int r = lane & 15, kg = lane >> 4;

  const unsigned short* a16 = (const unsigned short*)Av;
  const float*          a32 = (const float*)Av;

  uint4  sreg[4];
  float4 sregf[4][2];

  auto load_tile = [&](int t){
    #pragma unroll
    for (int it = 0; it < 4; ++it){
      int li = it*512 + tid;
      int rr = li >> 5, c16 = li & 31;
      int gr = t*64 + rr; if (gr >= Nn) gr = Nn - 1;
      if (AF32){
        const float* ap = a32 + (size_t)gr*256 + c16*8;
        sregf[it][0] = *reinterpret_cast<const float4*>(ap);
        sregf[it][1] = *reinterpret_cast<const float4*>(ap + 4);
      } else {
        sreg[it] = *reinterpret_cast<const uint4*>(a16 + (size_t)gr*256 + c16*8);
      }
    }
  };
  auto write_lds = [&](){
    #pragma unroll
    for (int it = 0; it < 4; ++it){
      int li = it*512 + tid;
      int rr = li >> 5, c16 = li & 31;
      if (AF32){
        float4 v0 = sregf[it][0], v1 = sregf[it][1];
        union { uint4 q; unsigned short s[8]; } u;
        u.s[0]=f2bf(v0.x); u.s[1]=f2bf(v0.y); u.s[2]=f2bf(v0.z); u.s[3]=f2bf(v0.w);
        u.s[4]=f2bf(v1.x); u.s[5]=f2bf(v1.y); u.s[6]=f2bf(v1.z); u.s[7]=f2bf(v1.w);
        *reinterpret_cast<uint4*>(&As[rr][c16*8]) = u.q;
      } else {
        *reinterpret_cast<uint4*>(&As[rr][c16*8]) = sreg[it];
      }
    }
  };

  float as_c[4], ad_c[4];
  #pragma unroll
  for (int c = 0; c < 4; ++c){
    as_c[c] = asrc[w*64 + c*16 + r];
    ad_c[c] = adst[w*64 + c*16 + r];
  }

  int t = blockIdx.x;
  if (t >= T) return;
  load_tile(t);

  for (;;){
    write_lds();
    __syncthreads();
    int tn = t + G;
    bool more = (tn < T);
    if (more) load_tile(tn);          // prefetch next tile while computing this one

    f32x4 acc[2][4] = {};
    #pragma unroll
    for (int k0 = 0; k0 < 256; k0 += 32){
      bf16x8 a0 = *reinterpret_cast<const bf16x8*>(&As[rh*32 +      r][kg*8 + k0]);
      bf16x8 a1 = *reinterpret_cast<const bf16x8*>(&As[rh*32 + 16 + r][kg*8 + k0]);
      #pragma unroll
      for (int c = 0; c < 4; ++c){
        bf16x8 bfr = *reinterpret_cast<const bf16x8*>(Wt + (size_t)(w*64 + c*16 + r)*256 + kg*8 + k0);
        acc[0][c] = __builtin_amdgcn_mfma_f32_16x16x32_bf16(a0, bfr, acc[0][c], 0, 0, 0);
        acc[1][c] = __builtin_amdgcn_mfma_f32_16x16x32_bf16(a1, bfr, acc[1][c], 0, 0, 0);
      }
    }

    // attention logits from registers
    #pragma unroll
    for (int n = 0; n < 2; ++n){
      #pragma unroll
      for (int i = 0; i < 4; ++i){
        float ps = acc[n][0][i]*as_c[0] + acc[n][1][i]*as_c[1]
                 + acc[n][2][i]*as_c[2] + acc[n][3][i]*as_c[3];
        float pd = acc[n][0][i]*ad_c[0] + acc[n][1][i]*ad_c[1]
                 + acc[n][2][i]*ad_c[2] + acc[n][3][i]*ad_c[3];
        #pragma unroll
        for (int off = 1; off < 16; off <<= 1){
          ps += __shfl_xor(ps, off, 64);
          pd += __shfl_xor(pd, off, 64);
        }
        int row = t*64 + rh*32 + n*16 + kg*4 + i;
        if (r == 0 && row < Nn){
          als[row*4 + w] = ps;
          ald[row*4 + w] = pd;
        }
      }
    }

    // C tile -> LDS (reuse As) -> coalesced global store
    __syncthreads();                  // everyone done reading As
    #pragma unroll
    for (int n = 0; n < 2; ++n){
      #pragma unroll
      for (int i = 0; i < 4; ++i){
        int lrow = rh*32 + n*16 + kg*4 + i;
        #pragma unroll
        for (int c = 0; c < 4; ++c)
          As[lrow][w*64 + c*16 + r] = f2bf(acc[n][c][i]);
      }
    }
    __syncthreads();
    #pragma unroll
    for (int it = 0; it < 4; ++it){
      int li = it*512 + tid;
      int rr = li >> 5, c16 = li & 31;
      int grow = t*64 + rr;
      if (grow < Nn){
        uint4 v = *reinterpret_cast<const uint4*>(&As[rr][c16*8]);
        *reinterpret_cast<uint4*>(H + (size_t)grow*256 + c16*8) = v;
      }
    }

    if (!more) break;
    __syncthreads();                  // C-readback done; safe to overwrite As
    t = tn;
  }
}

// ---------------- fused softmax + weighted gather ----------------
// NPF = edge-pairs in flight per step (4 or 8). Per 64-edge chunk each lane computes
// its own edge's 4-head exp-weights once (coalesced als gather) into an LDS table;
// denominator kept as per-lane partials. Inner loop per pair: bperm src, 512B row
// load, 4B LDS weight read, packed f32x2 FMA. No max subtraction (logits bounded;
// softmax shift-invariant).
template<int MODE, int NPF>
__global__ __launch_bounds__(256) void k_gather5(const unsigned short* __restrict__ Hm,
                          const int* __restrict__ rowptr, const int* __restrict__ srcs,
                          const float* __restrict__ als, const float* __restrict__ ald,
                          const float* __restrict__ bias,
                          unsigned short* __restrict__ actout, float* __restrict__ finalout, int Nn){
  __shared__ float wlds[4][64][4];
  int gid = blockIdx.x*blockDim.x + threadIdx.x;
  int node = gid >> 6, lane = gid & 63;
  if (node >= Nn) return;
  int wv_id = threadIdx.x >> 6;
  int half = lane >> 5;
  int l32  = lane & 31;
  int fbase = l32 * 8;
  int hd = l32 >> 3;
  unsigned voff = (unsigned)(l32 * 16);

  int beg = rowptr[node], deg = rowptr[node + 1] - beg;
  float4 adv = *reinterpret_cast<const float4*>(ald + (size_t)node*4);

  f32x2 acc2[4][4];
  #pragma unroll
  for (int u = 0; u < 4; ++u)
    #pragma unroll
    for (int q = 0; q < 4; ++q) acc2[u][q] = (f32x2){0.f, 0.f};
  float sw0 = 0.f, sw1 = 0.f, sw2 = 0.f, sw3 = 0.f;

  const char* Hb = (const char*)Hm;
  const float* wrow = &wlds[wv_id][0][0];

  for (int cb = 0; cb < deg; cb += 64){
    int chunk = min(64, deg - cb);
    bool valid = (lane < chunk);
    int mysrc = valid ? srcs[beg + cb + lane] : 0;

    float4 a = *reinterpret_cast<const float4*>(als + (size_t)mysrc*4);
    float l0 = a.x + adv.x; l0 = l0 > 0.f ? l0 : 0.2f*l0;
    float l1 = a.y + adv.y; l1 = l1 > 0.f ? l1 : 0.2f*l1;
    float l2 = a.z + adv.z; l2 = l2 > 0.f ? l2 : 0.2f*l2;
    float l3 = a.w + adv.w; l3 = l3 > 0.f ? l3 : 0.2f*l3;
    float4 wvv;
    wvv.x = valid ? __expf(l0) : 0.f;
    wvv.y = valid ? __expf(l1) : 0.f;
    wvv.z = valid ? __expf(l2) : 0.f;
    wvv.w = valid ? __expf(l3) : 0.f;
    sw0 += wvv.x; sw1 += wvv.y; sw2 += wvv.z; sw3 += wvv.w;
    *reinterpret_cast<float4*>(&wlds[wv_id][lane][0]) = wvv;
    asm volatile("s_waitcnt lgkmcnt(0)" ::: "memory");
    __builtin_amdgcn_sched_barrier(0);

    for (int e = 0; e < chunk; e += NPF*2){
      uint4 hw[NPF]; float wgt[NPF];
      #pragma unroll
      for (int u = 0; u < NPF; ++u){
        int pe = e + 2*u;
        int sM = __shfl(mysrc, pe + half, 64);
        hw[u] = *reinterpret_cast<const uint4*>(Hb + (unsigned)sM*512u + voff);
        wgt[u] = wrow[(unsigned)(pe + half)*4u + (unsigned)hd];
      }
      #pragma unroll
      for (int u = 0; u < NPF; ++u){
        f32x2 w2 = {wgt[u], wgt[u]};
        acc2[u & 3][0] += w2 * bf2x(hw[u].x);
        acc2[u & 3][1] += w2 * bf2x(hw[u].y);
        acc2[u & 3][2] += w2 * bf2x(hw[u].z);
        acc2[u & 3][3] += w2 * bf2x(hw[u].w);
      }
    }
  }

  // reduce denominators across the wave
  #pragma unroll
  for (int off = 1; off < 64; off <<= 1){
    sw0 += __shfl_xor(sw0, off, 64);
    sw1 += __shfl_xor(sw1, off, 64);
    sw2 += __shfl_xor(sw2, off, 64);
    sw3 += __shfl_xor(sw3, off, 64);
  }
  float sden = (hd == 0) ? sw0 : (hd == 1) ? sw1 : (hd == 2) ? sw2 : sw3;
  float inv = 1.f / sden;

  float accf[8];
  #pragma unroll
  for (int q = 0; q < 4; ++q){
    f32x2 s2 = acc2[0][q] + acc2[1][q] + acc2[2][q] + acc2[3][q];
    float t0 = s2[0], t1 = s2[1];
    t0 += __shfl_xor(t0, 32, 64);
    t1 += __shfl_xor(t1, 32, 64);
    accf[2*q]   = t0;
    accf[2*q+1] = t1;
  }

  if (MODE == 0){
    if (lane < 32){
      float4 b0 = *reinterpret_cast<const float4*>(bias + fbase);
      float4 b1 = *reinterpret_cast<const float4*>(bias + fbase + 4);
      float o[8];
      o[0] = accf[0]*inv + b0.x; o[1] = accf[1]*inv + b0.y;
      o[2] = accf[2]*inv + b0.z; o[3] = accf[3]*inv + b0.w;
      o[4] = accf[4]*inv + b1.x; o[5] = accf[5]*inv + b1.y;
      o[6] = accf[6]*inv + b1.z; o[7] = accf[7]*inv + b1.w;
      u16x8 pk;
      #pragma unroll
      for (int i = 0; i < 8; ++i){
        float v = o[i];
        v = v > 0.f ? v : __expf(v) - 1.f;
        pk[i] = f2bf(v);
      }
      *reinterpret_cast<u16x8*>(actout + (size_t)node*256 + fbase) = pk;
    }
  } else {
    float v[8];
    #pragma unroll
    for (int i = 0; i < 8; ++i){
      float t = accf[i]*inv;
      t += __shfl_xor(t, 8, 64);
      t += __shfl_xor(t, 16, 64);
      v[i] = t;
    }
    int k = l32 & 7;
    float4 b0 = *reinterpret_cast<const float4*>(bias + k*8);
    float4 b1 = *reinterpret_cast<const float4*>(bias + k*8 + 4);
    v[0] = v[0]*0.25f + b0.x; v[1] = v[1]*0.25f + b0.y;
    v[2] = v[2]*0.25f + b0.z; v[3] = v[3]*0.25f + b0.w;
    v[4] = v[4]*0.25f + b1.x; v[5] = v[5]*0.25f + b1.y;
    v[6] = v[6]*0.25f + b1.z; v[7] = v[7]*0.25f + b1.w;
    float mx = v[0];
    #pragma unroll
    for (int i = 1; i < 8; ++i) mx = fmaxf(mx, v[i]);
    #pragma unroll
    for (int off = 1; off < 8; off <<= 1) mx = fmaxf(mx, __shfl_xor(mx, off, 64));
    float se = 0.f;
    #pragma unroll
    for (int i = 0; i < 8; ++i) se += __expf(v[i] - mx);
    #pragma unroll
    for (int off = 1; off < 8; off <<= 1) se += __shfl_xor(se, off, 64);
    float lse = mx + __logf(se);
    if (lane < 8){
      float4 o0, o1;
      o0.x = v[0]-lse; o0.y = v[1]-lse; o0.z = v[2]-lse; o0.w = v[3]-lse;
      o1.x = v[4]-lse; o1.y = v[5]-lse; o1.z = v[6]-lse; o1.w = v[7]-lse;
      float* dst = finalout + (size_t)node*64 + lane*8;
      *reinterpret_cast<float4*>(dst)     = o0;
      *reinterpret_cast<float4*>(dst + 4) = o1;
    }
  }
}

extern "C" void kernel_launch(void* const* d_in, const int* in_sizes, int n_in,
                              void* d_out, int out_size, void* d_ws, size_t ws_size,
                              hipStream_t stream){
  const float* x     = (const float*)d_in[0];
  const int*   ei    = (const int*)  d_in[1];
  const float* W1    = (const float*)d_in[2];
  const float* asrc1 = (const float*)d_in[3];
  const float* adst1 = (const float*)d_in[4];
  const float* b1    = (const float*)d_in[5];
  const float* W2    = (const float*)d_in[6];
  const float* asrc2 = (const float*)d_in[7];
  const float* adst2 = (const float*)d_in[8];
  const float* b2    = (const float*)d_in[9];
  const float* W3    = (const float*)d_in[10];
  const float* asrc3 = (const float*)d_in[11];
  const float* adst3 = (const float*)d_in[12];
  const float* b3    = (const float*)d_in[13];
  float* out = (float*)d_out;

  int N = in_sizes[0] / 256;
  int E = in_sizes[1] / 2;

  char* p = (char*)d_ws;
  auto carve = [&](size_t bytes){ void* r = (void*)p; p += (bytes + 511) & ~(size_t)511; return r; };
  unsigned short* bufA = (unsigned short*)carve((size_t)N*256*2);
  unsigned short* bufH = (unsigned short*)carve((size_t)N*256*2);
  unsigned short* bufB = (unsigned short*)carve((size_t)N*256*2);
  unsigned short* wt1  = (unsigned short*)carve(256*256*2);
  unsigned short* wt2  = (unsigned short*)carve(256*256*2);
  unsigned short* wt3  = (unsigned short*)carve(256*256*2);
  float* als    = (float*)carve((size_t)N*4*4);
  float* ald    = (float*)carve((size_t)N*4*4);
  int* rowptr   = (int*)carve((size_t)(N+1)*4);
  int* counts   = (int*)carve((size_t)N*4);
  int* cursor   = (int*)carve((size_t)N*4);
  int* bsum     = (int*)carve((size_t)1024*4);
  int* srcs     = (int*)carve((size_t)(E+N)*4);

  // CSR build
  hipMemsetAsync(counts, 0, (size_t)N*4, stream);
  k_hist<<<2048, 256, 0, stream>>>(ei, E, N, counts);
  int nb = (N + 1023) / 1024;
  k_scan1<<<nb, 1024, 0, stream>>>(counts, rowptr, bsum, N);
  k_scan2<<<1, 1024, 0, stream>>>(bsum, nb);
  k_scan3<<<(N + 255)/256, 256, 0, stream>>>(rowptr, bsum, counts, cursor, N);
  k_scatter<<<2048, 256, 0, stream>>>(ei, E, N, cursor, srcs);

  k_transpose_all<<<768, 256, 0, stream>>>(W1, W2, W3, wt1, wt2, wt3);

  int T = (N + 63) / 64;
  int G = (T + 1) / 2;               // two tiles per block, pipelined
  int nodeblocks = (N*64 + 255)/256;

  // layer 1 (A = x in f32, converted during staging); gather variant A (NPF=8)
  k_gemm4<true><<<G, 512, 0, stream>>>(x, wt1, asrc1, adst1, bufH, als, ald, N, T, G);
  k_gather5<0,8><<<nodeblocks, 256, 0, stream>>>(bufH, rowptr, srcs, als, ald, b1, bufB, nullptr, N);
  // layer 2; gather variant B (NPF=4)
  k_gemm4<false><<<G, 512, 0, stream>>>(bufB, wt2, asrc2, adst2, bufH, als, ald, N, T, G);
  k_gather5<0,4><<<nodeblocks, 256, 0, stream>>>(bufH, rowptr, srcs, als, ald, b2, bufA, nullptr, N);
  // layer 3
  k_gemm4<false><<<G, 512, 0, stream>>>(bufA, wt3, asrc3, adst3, bufH, als, ald, N, T, G);
  k_gather5<1,8><<<nodeblocks, 256, 0, stream>>>(bufH, rowptr, srcs, als, ald, b3, nullptr, out, N);
}